// Round 12
// baseline (2736.507 us; speedup 1.0000x reference)
//
#include <hip/hip_runtime.h>
#include <hip/hip_cooperative_groups.h>
#include <math.h>

namespace cg = cooperative_groups;

#define NB 64
#define DIM 128
#define ETOT 1048576
#define EPG 16384   // edges per graph
#define EPT 16      // edges per thread (1024 threads)
#define NBLK 256    // cooperative grid size (1 block/CU)

struct Params {
    const float* x_in;
    const int* ei;
    const float* cw[5];
    const float* cb[5];
    const float* pw[5];
    const float *l1w, *l1b, *l2w, *l2b, *l3w, *l3b;
    float* out;
    float *xA, *xB, *xL;
    int *src, *dst;
    int2* epack;
    int *cnt, *eoff;
    float *dinv, *score, *hsum, *invn;
};

__device__ __forceinline__ float4 f4shfl32(float4 v) {
    v.x = __shfl_xor(v.x, 32, 64);
    v.y = __shfl_xor(v.y, 32, 64);
    v.z = __shfl_xor(v.z, 32, 64);
    v.w = __shfl_xor(v.w, 32, 64);
    return v;
}

__global__ __launch_bounds__(1024, 4) void mega_kernel(Params p) {
    __shared__ alignas(16) char LB[57344];
    const int b = blockIdx.x;
    const int t = threadIdx.x;
    const int lane = t & 63;
    const int wvi = t >> 6;
    const int NS_D[6] = {1024, 820, 656, 525, 420, 336};
    cg::grid_group grid = cg::this_grid();

    // ================= init: edge copy, histogram, scan, epack scatter =================
    if (b < NB) {
        int* hs = (int*)(LB);
        int* hc = (int*)(LB + 4096);
        int* cur = (int*)(LB + 8192);
        float* dv = (float*)(LB + 12288);
        float* shf = (float*)(LB + 16384);
        int* wsum = (int*)(LB + 16896);
        const int g = b;
        hs[t] = 0; hc[t] = 0;
        if (t < 256) p.hsum[g * 256 + t] = 0.f;
        __syncthreads();
        const int b0 = g * EPG;
        int sr[EPT], dr[EPT];
#pragma unroll
        for (int q = 0; q < EPT; q++) {
            int e = b0 + q * 1024 + t;
            int s = p.ei[e], d = p.ei[ETOT + e];
            sr[q] = s; dr[q] = d;
            p.src[e] = s; p.dst[e] = d;
            atomicAdd(&hs[s & 1023], 1);
            atomicAdd(&hc[d & 1023], 1);
        }
        __syncthreads();
        int v = hc[t];
        dv[t] = rsqrtf((float)hs[t] + 1.0f);
        int s = v;
#pragma unroll
        for (int off = 1; off < 64; off <<= 1) {
            int u = __shfl_up(s, off, 64);
            if (lane >= off) s += u;
        }
        if (lane == 63) wsum[wvi] = s;
        __syncthreads();
        if (wvi == 0) {
            int ws = (lane < 16) ? wsum[lane] : 0;
#pragma unroll
            for (int off = 1; off < 16; off <<= 1) {
                int u = __shfl_up(ws, off, 64);
                if (lane >= off) ws += u;
            }
            if (lane < 16) wsum[lane] = ws;
        }
        __syncthreads();
        int excl = b0 + s + ((wvi > 0) ? wsum[wvi - 1] : 0) - v;
        p.eoff[g * 1024 + t] = excl;
        p.cnt[g * 1024 + t] = v;
        p.dinv[g * 1024 + t] = dv[t];
        cur[t] = excl;
        __syncthreads();
#pragma unroll
        for (int q = 0; q < EPT; q++) {
            int sl = sr[q] & 1023, dl = dr[q] & 1023;
            int pos = atomicAdd(&cur[dl], 1);
            p.epack[pos] = make_int2(sr[q], __float_as_int(dv[sl] * dv[dl]));
        }
        if (g == 0) {
            if (t < 128) shf[t] = p.pw[0][t] * p.pw[0][t];
            __syncthreads();
            for (int q = 64; q > 0; q >>= 1) {
                if (t < q) shf[t] += shf[t + q];
                __syncthreads();
            }
            if (t == 0) p.invn[0] = rsqrtf(shf[0]);
        }
    }
    __threadfence();
    grid.sync();

    const float* xin = p.x_in;
    for (int layer = 0; layer < 5; layer++) {
        const int n = NS_D[layer], k = NS_D[layer + 1];
        const int N = NB * n;
        const int last = (layer == 4);

        // ================= linear: xL = xin @ W.T + b (128n x 128f tiles) =================
        {
            float* Wt = (float*)(LB);            // 32 x 192
            float* xT = (float*)(LB + 24576);    // 32 x 192
            const float* W = p.cw[layer];
            const int nf = t & 31;     // node frag (4 nodes)
            const int u = t >> 5;      // feat frag (4 feats)
            float bv[4];
#pragma unroll
            for (int f = 0; f < 4; f++) bv[f] = p.cb[layer][u * 4 + f];
            const int ntiles = (N + 127) >> 7;
            for (int tb = b; tb < ntiles; tb += NBLK) {
                const int base = tb << 7;
                float acc[4][4];
#pragma unroll
                for (int i = 0; i < 4; i++)
#pragma unroll
                    for (int f = 0; f < 4; f++) acc[i][f] = bv[f];
                for (int kb = 0; kb < 4; kb++) {
                    __syncthreads();
                    {
                        const int dq = t >> 7;            // wave-uniform
                        const int r = t & 127;
                        const int sl = (r >> 3) * 12 + (r & 7);
                        float4 w4 = *(const float4*)(W + r * 128 + kb * 32 + dq * 4);
                        Wt[(dq * 4 + 0) * 192 + sl] = w4.x;
                        Wt[(dq * 4 + 1) * 192 + sl] = w4.y;
                        Wt[(dq * 4 + 2) * 192 + sl] = w4.z;
                        Wt[(dq * 4 + 3) * 192 + sl] = w4.w;
                        const int nd = base + r;
                        float4 x4 = (nd < N) ? *(const float4*)(xin + (size_t)nd * DIM + kb * 32 + dq * 4)
                                             : make_float4(0.f, 0.f, 0.f, 0.f);
                        xT[(dq * 4 + 0) * 192 + sl] = x4.x;
                        xT[(dq * 4 + 1) * 192 + sl] = x4.y;
                        xT[(dq * 4 + 2) * 192 + sl] = x4.z;
                        xT[(dq * 4 + 3) * 192 + sl] = x4.w;
                    }
                    __syncthreads();
#pragma unroll 4
                    for (int d = 0; d < 32; d++) {
                        float4 xv = *(const float4*)&xT[d * 192 + (nf >> 1) * 12 + (nf & 1) * 4];
                        float4 wq = *(const float4*)&Wt[d * 192 + (u >> 1) * 12 + (u & 1) * 4];
                        float xs[4] = {xv.x, xv.y, xv.z, xv.w};
                        float ws[4] = {wq.x, wq.y, wq.z, wq.w};
#pragma unroll
                        for (int i = 0; i < 4; i++)
#pragma unroll
                            for (int f = 0; f < 4; f++) acc[i][f] += xs[i] * ws[f];
                    }
                }
#pragma unroll
                for (int i = 0; i < 4; i++) {
                    const int nd = base + nf * 4 + i;
                    if (nd < N)
                        *(float4*)(p.xL + (size_t)nd * DIM + u * 4) =
                            make_float4(acc[i][0], acc[i][1], acc[i][2], acc[i][3]);
                }
            }
        }
        __threadfence();
        grid.sync();

        // ================= agg: xA = relu(D^-1 self + gather) + score =================
        {
            const int gpb = (n + 31) >> 5;
            const int units = NB * gpb;
            const int l32 = t & 31;
            for (int uu = b; uu < units; uu += NBLK) {
                const int g = uu & 63;
                const int ln = (uu >> 6) * 32 + (t >> 5);
                if (ln >= n) continue;
                const int node = g * n + ln;
                float dsn = p.dinv[node];
                float4 sv = ((const float4*)(p.xL + (size_t)node * DIM))[l32];
                float w0 = dsn * dsn;
                float4 a0 = make_float4(sv.x * w0, sv.y * w0, sv.z * w0, sv.w * w0);
                float4 a1 = make_float4(0.f, 0.f, 0.f, 0.f);
                float4 a2 = make_float4(0.f, 0.f, 0.f, 0.f);
                float4 a3 = make_float4(0.f, 0.f, 0.f, 0.f);
                int s0 = p.eoff[node], s1 = s0 + p.cnt[node];
                int j = s0;
                for (; j + 3 < s1; j += 4) {
                    int2 e0 = p.epack[j], e1 = p.epack[j + 1];
                    int2 e2 = p.epack[j + 2], e3 = p.epack[j + 3];
                    float4 x0 = ((const float4*)(p.xL + (size_t)e0.x * DIM))[l32];
                    float4 x1 = ((const float4*)(p.xL + (size_t)e1.x * DIM))[l32];
                    float4 x2 = ((const float4*)(p.xL + (size_t)e2.x * DIM))[l32];
                    float4 x3 = ((const float4*)(p.xL + (size_t)e3.x * DIM))[l32];
                    float n0 = __int_as_float(e0.y), n1 = __int_as_float(e1.y);
                    float n2 = __int_as_float(e2.y), n3 = __int_as_float(e3.y);
                    a0.x += n0 * x0.x; a0.y += n0 * x0.y; a0.z += n0 * x0.z; a0.w += n0 * x0.w;
                    a1.x += n1 * x1.x; a1.y += n1 * x1.y; a1.z += n1 * x1.z; a1.w += n1 * x1.w;
                    a2.x += n2 * x2.x; a2.y += n2 * x2.y; a2.z += n2 * x2.z; a2.w += n2 * x2.w;
                    a3.x += n3 * x3.x; a3.y += n3 * x3.y; a3.z += n3 * x3.z; a3.w += n3 * x3.w;
                }
                for (; j < s1; j++) {
                    int2 e0 = p.epack[j];
                    float n0 = __int_as_float(e0.y);
                    float4 x0 = ((const float4*)(p.xL + (size_t)e0.x * DIM))[l32];
                    a0.x += n0 * x0.x; a0.y += n0 * x0.y; a0.z += n0 * x0.z; a0.w += n0 * x0.w;
                }
                float4 av = make_float4(fmaxf(a0.x + a1.x + a2.x + a3.x, 0.f),
                                        fmaxf(a0.y + a1.y + a2.y + a3.y, 0.f),
                                        fmaxf(a0.z + a1.z + a2.z + a3.z, 0.f),
                                        fmaxf(a0.w + a1.w + a2.w + a3.w, 0.f));
                ((float4*)(p.xA + (size_t)node * DIM))[l32] = av;
                float4 pv = ((const float4*)p.pw[layer])[l32];
                float dot = av.x * pv.x + av.y * pv.y + av.z * pv.z + av.w * pv.w;
                for (int off = 16; off >= 1; off >>= 1) dot += __shfl_xor(dot, off, 32);
                if (l32 == 0) p.score[node] = tanhf(dot * p.invn[0]);
            }
        }
        __threadfence();
        grid.sync();

        // ================= pool (blocks 0..63): sort+gather+readout (+CSR | +head) ======
        if (b < NB) {
            float* key0 = (float*)(LB);
            float* key1 = (float*)(LB + 4096);
            int* idx0 = (int*)(LB + 8192);
            int* idx1 = (int*)(LB + 12288);
            int* nid = (int*)(LB + 16384);
            float4* srm = (float4*)(LB + 20480);   // [16*33]
            float4* srs = (float4*)(LB + 28928);   // [16*33]
            int* hs = (int*)(LB + 37376);
            int* hc = (int*)(LB + 41472);
            int* cur = (int*)(LB + 45568);
            float* dv = (float*)(LB + 49664);
            float* shf = (float*)(LB + 53760);
            int* wsum = (int*)(LB + 54272);
            float* hr = (float*)(LB + 54336);
            float* h1 = (float*)(LB + 55360);
            float* h2 = (float*)(LB + 55872);
            float* lz = (float*)(LB + 56128);
            const int g = b;
            float k_r = (t < n) ? p.score[g * n + t] : -2.0f;
            int i_r = t;
            hs[t] = 0; hc[t] = 0;
            int par = 0;
            for (unsigned ksz = 2; ksz <= 1024; ksz <<= 1) {
                for (unsigned jj = ksz >> 1; jj > 0; jj >>= 1) {
                    float kq; int iq;
                    if (jj >= 64) {
                        float* kc = par ? key1 : key0;
                        int* ic = par ? idx1 : idx0;
                        kc[t] = k_r; ic[t] = i_r;
                        __syncthreads();
                        kq = kc[t ^ jj]; iq = ic[t ^ jj];
                        par ^= 1;
                    } else {
                        kq = __shfl_xor(k_r, (int)jj, 64);
                        iq = __shfl_xor(i_r, (int)jj, 64);
                    }
                    bool mineFirst = (k_r > kq) || (k_r == kq && i_r < iq);
                    bool up = ((t & ksz) == 0);
                    bool iAmLower = ((t & jj) == 0);
                    bool keepMine = (iAmLower == up) ? mineFirst : !mineFirst;
                    if (!keepMine) { k_r = kq; i_r = iq; }
                }
            }
            key0[t] = k_r; idx0[t] = i_r;
            nid[i_r] = (t < (unsigned)k) ? t : -1;
            __syncthreads();
            // gather + readout
            const int lane4 = t & 31;
            const int ch = t >> 5;
            float4 mx = make_float4(-INFINITY, -INFINITY, -INFINITY, -INFINITY);
            float4 sm = make_float4(0.f, 0.f, 0.f, 0.f);
            for (int j = ch; j < k; j += 32) {
                int row = idx0[j];
                float sval = key0[j];
                float4 vv = ((const float4*)(p.xA + ((size_t)g * n + row) * DIM))[lane4];
                vv.x *= sval; vv.y *= sval; vv.z *= sval; vv.w *= sval;
                if (!last) ((float4*)(p.xB + ((size_t)g * k + j) * DIM))[lane4] = vv;
                mx.x = fmaxf(mx.x, vv.x); mx.y = fmaxf(mx.y, vv.y);
                mx.z = fmaxf(mx.z, vv.z); mx.w = fmaxf(mx.w, vv.w);
                sm.x += vv.x; sm.y += vv.y; sm.z += vv.z; sm.w += vv.w;
            }
            {
                float4 mo = f4shfl32(mx);
                mx.x = fmaxf(mx.x, mo.x); mx.y = fmaxf(mx.y, mo.y);
                mx.z = fmaxf(mx.z, mo.z); mx.w = fmaxf(mx.w, mo.w);
                float4 so = f4shfl32(sm);
                sm.x += so.x; sm.y += so.y; sm.z += so.z; sm.w += so.w;
            }
            if ((ch & 1) == 0) { srm[(ch >> 1) * 33 + lane4] = mx; srs[(ch >> 1) * 33 + lane4] = sm; }
            __syncthreads();
            for (int ss = 8; ss >= 1; ss >>= 1) {
                if (ch < ss) {
                    float4 a = srm[ch * 33 + lane4], bq = srm[(ch + ss) * 33 + lane4];
                    a.x = fmaxf(a.x, bq.x); a.y = fmaxf(a.y, bq.y);
                    a.z = fmaxf(a.z, bq.z); a.w = fmaxf(a.w, bq.w);
                    srm[ch * 33 + lane4] = a;
                    float4 c = srs[ch * 33 + lane4], d = srs[(ch + ss) * 33 + lane4];
                    c.x += d.x; c.y += d.y; c.z += d.z; c.w += d.w;
                    srs[ch * 33 + lane4] = c;
                }
                __syncthreads();
            }
            if (ch == 0) {
                float4 m = srm[lane4];
                float4 s4 = srs[lane4];
                float invk = 1.0f / (float)k;
                int f0 = lane4 * 4;
                if (!last) {
                    float* hp = p.hsum + g * 256;
                    hp[f0 + 0] += m.x; hp[f0 + 1] += m.y; hp[f0 + 2] += m.z; hp[f0 + 3] += m.w;
                    hp[128 + f0 + 0] += s4.x * invk; hp[128 + f0 + 1] += s4.y * invk;
                    hp[128 + f0 + 2] += s4.z * invk; hp[128 + f0 + 3] += s4.w * invk;
                } else {
                    const float* hp = p.hsum + g * 256;
                    hr[f0 + 0] = hp[f0 + 0] + m.x; hr[f0 + 1] = hp[f0 + 1] + m.y;
                    hr[f0 + 2] = hp[f0 + 2] + m.z; hr[f0 + 3] = hp[f0 + 3] + m.w;
                    hr[128 + f0 + 0] = hp[128 + f0 + 0] + s4.x * invk;
                    hr[128 + f0 + 1] = hp[128 + f0 + 1] + s4.y * invk;
                    hr[128 + f0 + 2] = hp[128 + f0 + 2] + s4.z * invk;
                    hr[128 + f0 + 3] = hp[128 + f0 + 3] + s4.w * invk;
                }
            }
            if (last) {
                __syncthreads();
                if (t < 128) {
                    float a1 = p.l1b[t];
                    for (int d = 0; d < 256; d++) a1 += hr[d] * p.l1w[t * 256 + d];
                    h1[t] = fmaxf(a1, 0.f);
                }
                __syncthreads();
                if (t < 64) {
                    float a2 = p.l2b[t];
                    for (int d = 0; d < 128; d++) a2 += h1[d] * p.l2w[t * 128 + d];
                    h2[t] = fmaxf(a2, 0.f);
                }
                __syncthreads();
                if (t < 2) {
                    float a3 = p.l3b[t];
                    for (int d = 0; d < 64; d++) a3 += h2[d] * p.l3w[t * 64 + d];
                    lz[t] = a3;
                }
                __syncthreads();
                if (t < 2) {
                    float z0 = lz[0], z1 = lz[1];
                    float m = fmaxf(z0, z1);
                    float lse = m + logf(expf(z0 - m) + expf(z1 - m));
                    p.out[g * 2 + t] = lz[t] - lse;
                }
            } else {
                // remap + histogram + scan + scatter for next layer
                const int b0 = g * EPG, gn = g * n, gk = g * k;
                int sr[EPT], dr[EPT];
#pragma unroll
                for (int q = 0; q < EPT; q++) {
                    int e = b0 + q * 1024 + t;
                    int s = p.src[e];
                    int s2 = -1, d2 = -1;
                    if (s >= 0) {
                        s2 = nid[s - gn];
                        d2 = nid[p.dst[e] - gn];
                        if (s2 >= 0 && d2 >= 0) {
                            p.src[e] = gk + s2;
                            p.dst[e] = gk + d2;
                            atomicAdd(&hs[s2], 1);
                            atomicAdd(&hc[d2], 1);
                        } else {
                            p.src[e] = -1;
                            p.dst[e] = -1;
                            s2 = -1;
                        }
                    }
                    sr[q] = s2; dr[q] = d2;
                }
                __syncthreads();
                int v = (t < k) ? hc[t] : 0;
                if (t < k) dv[t] = rsqrtf((float)hs[t] + 1.0f);
                int s = v;
#pragma unroll
                for (int off = 1; off < 64; off <<= 1) {
                    int u = __shfl_up(s, off, 64);
                    if (lane >= off) s += u;
                }
                if (lane == 63) wsum[wvi] = s;
                __syncthreads();
                if (wvi == 0) {
                    int ws = (lane < 16) ? wsum[lane] : 0;
#pragma unroll
                    for (int off = 1; off < 16; off <<= 1) {
                        int u = __shfl_up(ws, off, 64);
                        if (lane >= off) ws += u;
                    }
                    if (lane < 16) wsum[lane] = ws;
                }
                __syncthreads();
                if (t < k) {
                    int excl = b0 + s + ((wvi > 0) ? wsum[wvi - 1] : 0) - v;
                    p.eoff[gk + t] = excl;
                    p.cnt[gk + t] = v;
                    p.dinv[gk + t] = dv[t];
                    cur[t] = excl;
                }
                __syncthreads();
#pragma unroll
                for (int q = 0; q < EPT; q++) {
                    if (sr[q] >= 0) {
                        int pos = atomicAdd(&cur[dr[q]], 1);
                        p.epack[pos] = make_int2(gk + sr[q], __float_as_int(dv[sr[q]] * dv[dr[q]]));
                    }
                }
                if (g == 0) {
                    if (t < 128) shf[t] = p.pw[layer + 1][t] * p.pw[layer + 1][t];
                    __syncthreads();
                    for (int q = 64; q > 0; q >>= 1) {
                        if (t < q) shf[t] += shf[t + q];
                        __syncthreads();
                    }
                    if (t == 0) p.invn[0] = rsqrtf(shf[0]);
                }
            }
        }
        if (layer < 4) {
            __threadfence();
            grid.sync();
        }
        xin = p.xB;
    }
}

extern "C" void kernel_launch(void* const* d_in, const int* in_sizes, int n_in,
                              void* d_out, int out_size, void* d_ws, size_t ws_size,
                              hipStream_t stream) {
    Params p;
    p.x_in = (const float*)d_in[0];
    p.ei = (const int*)d_in[1];
    for (int i = 0; i < 5; i++) {
        p.cw[i] = (const float*)d_in[3 + 3 * i];
        p.cb[i] = (const float*)d_in[4 + 3 * i];
        p.pw[i] = (const float*)d_in[5 + 3 * i];
    }
    p.l1w = (const float*)d_in[18];
    p.l1b = (const float*)d_in[19];
    p.l2w = (const float*)d_in[20];
    p.l2b = (const float*)d_in[21];
    p.l3w = (const float*)d_in[22];
    p.l3b = (const float*)d_in[23];
    p.out = (float*)d_out;

    char* w = (char*)d_ws;
    p.xA    = (float*)w; w += (size_t)65536 * DIM * 4;
    p.xB    = (float*)w; w += (size_t)65536 * DIM * 4;
    p.xL    = (float*)w; w += (size_t)65536 * DIM * 4;
    p.src   = (int*)w;   w += (size_t)ETOT * 4;
    p.dst   = (int*)w;   w += (size_t)ETOT * 4;
    p.epack = (int2*)w;  w += (size_t)ETOT * 8;
    p.cnt   = (int*)w;   w += (size_t)65536 * 4;
    p.eoff  = (int*)w;   w += (size_t)65536 * 4;
    p.dinv  = (float*)w; w += (size_t)65536 * 4;
    p.score = (float*)w; w += (size_t)65536 * 4;
    p.hsum  = (float*)w; w += (size_t)NB * 256 * 4;
    p.invn  = (float*)w; w += 4;

    void* kargs[] = { (void*)&p };
    hipError_t err = hipLaunchCooperativeKernel((const void*)mega_kernel, dim3(NBLK),
                                                dim3(1024), kargs, 0, stream);
    (void)err;
}

// Round 13
// 535.794 us; speedup vs baseline: 5.1074x; 5.1074x over previous
//
#include <hip/hip_runtime.h>
#include <math.h>

#define NB 64
#define DIM 128
#define ETOT 1048576
#define EPG 16384   // edges-per-graph region (ETOT / NB)
#define EPT 16      // edges per thread in 1024-thread per-graph kernels
#define WRS 192     // LDS row stride (floats) for W tile
#define XRS 96      // LDS row stride for x tile

static const int NS_H[6] = {1024, 820, 656, 525, 420, 336};

// ---------------- init: edges->src/dst, histogram, scan, scatter epack, dinv, invn ----------------
__global__ __launch_bounds__(1024) void init_kernel(const int* __restrict__ ei,
                                  int* __restrict__ src, int* __restrict__ dst,
                                  int2* __restrict__ epack, int* __restrict__ eoff,
                                  int* __restrict__ cnt, float* __restrict__ dinv,
                                  float* __restrict__ invn, const float* __restrict__ pw0,
                                  float* __restrict__ hsum) {
    __shared__ int hs[1024], hc[1024], cur[1024];
    __shared__ float dv[1024];
    __shared__ float shf[128];
    __shared__ int wsum[16];
    int g = blockIdx.x, t = threadIdx.x;
    int lane = t & 63, wv = t >> 6;
    hs[t] = 0; hc[t] = 0;
    if (t < 256) hsum[g * 256 + t] = 0.f;
    __syncthreads();
    int b0 = g * EPG;
    int sr[EPT], dr[EPT];
#pragma unroll
    for (int q = 0; q < EPT; q++) {
        int e = b0 + q * 1024 + t;
        int s = ei[e], d = ei[ETOT + e];
        sr[q] = s; dr[q] = d;
        src[e] = s; dst[e] = d;
        atomicAdd(&hs[s & 1023], 1);
        atomicAdd(&hc[d & 1023], 1);
    }
    __syncthreads();
    int v = hc[t];
    dv[t] = rsqrtf((float)hs[t] + 1.0f);
    int s = v;
#pragma unroll
    for (int off = 1; off < 64; off <<= 1) {
        int u = __shfl_up(s, off, 64);
        if (lane >= off) s += u;
    }
    if (lane == 63) wsum[wv] = s;
    __syncthreads();
    if (wv == 0) {
        int ws = (lane < 16) ? wsum[lane] : 0;
#pragma unroll
        for (int off = 1; off < 16; off <<= 1) {
            int u = __shfl_up(ws, off, 64);
            if (lane >= off) ws += u;
        }
        if (lane < 16) wsum[lane] = ws;
    }
    __syncthreads();
    int excl = b0 + s + ((wv > 0) ? wsum[wv - 1] : 0) - v;
    eoff[g * 1024 + t] = excl;
    cnt[g * 1024 + t] = v;
    dinv[g * 1024 + t] = dv[t];
    cur[t] = excl;
    __syncthreads();
#pragma unroll
    for (int q = 0; q < EPT; q++) {
        int sl = sr[q] & 1023, dl = dr[q] & 1023;
        int pos = atomicAdd(&cur[dl], 1);
        epack[pos] = make_int2(sr[q], __float_as_int(dv[sl] * dv[dl]));
    }
    if (g == 0) {
        if (t < 128) shf[t] = pw0[t] * pw0[t];
        __syncthreads();
        for (int q = 64; q > 0; q >>= 1) {
            if (t < q) shf[t] += shf[t + q];
            __syncthreads();
        }
        if (t == 0) invn[0] = rsqrtf(shf[0]);
    }
}

// ---------------- linear: y = x @ W.T + b (64n x 128f tile, conflict-free swizzle) ----------------
__global__ __launch_bounds__(256) void linear_kernel(const float* __restrict__ x,
                              const float* __restrict__ W, const float* __restrict__ b,
                              float* __restrict__ y, int N) {
    __shared__ float Wt[32 * WRS];
    __shared__ float xT[32 * XRS];
    int tid = threadIdx.x;
    int base = blockIdx.x * 64;
    int nf = tid & 15;
    int u  = tid >> 4;
    float acc[4][8];
    {
        float bv[8];
#pragma unroll
        for (int f = 0; f < 8; f++) bv[f] = b[u * 8 + f];
#pragma unroll
        for (int i = 0; i < 4; i++)
#pragma unroll
            for (int f = 0; f < 8; f++) acc[i][f] = bv[f];
    }
    for (int kb = 0; kb < 4; kb++) {
        __syncthreads();
#pragma unroll
        for (int q = 0; q < 4; q++) {
            int i = q * 256 + tid;
            int dq = i >> 7;
            int r = i & 127;
            int s = (r >> 3) * 12 + (r & 7);
            float4 wv = *(const float4*)(W + r * 128 + kb * 32 + dq * 4);
            Wt[(dq * 4 + 0) * WRS + s] = wv.x;
            Wt[(dq * 4 + 1) * WRS + s] = wv.y;
            Wt[(dq * 4 + 2) * WRS + s] = wv.z;
            Wt[(dq * 4 + 3) * WRS + s] = wv.w;
        }
#pragma unroll
        for (int q = 0; q < 2; q++) {
            int i = q * 256 + tid;
            int dq = i >> 6;
            int r = i & 63;
            int s = (r >> 3) * 12 + (r & 7);
            float4 xv = *(const float4*)(x + (size_t)(base + r) * DIM + kb * 32 + dq * 4);
            xT[(dq * 4 + 0) * XRS + s] = xv.x;
            xT[(dq * 4 + 1) * XRS + s] = xv.y;
            xT[(dq * 4 + 2) * XRS + s] = xv.z;
            xT[(dq * 4 + 3) * XRS + s] = xv.w;
        }
        __syncthreads();
#pragma unroll 4
        for (int d = 0; d < 32; d++) {
            float4 xv = *(const float4*)&xT[d * XRS + (nf >> 1) * 12 + (nf & 1) * 4];
            float4 wa = *(const float4*)&Wt[d * WRS + u * 12];
            float4 wb = *(const float4*)&Wt[d * WRS + u * 12 + 4];
            float xs[4] = {xv.x, xv.y, xv.z, xv.w};
            float ws[8] = {wa.x, wa.y, wa.z, wa.w, wb.x, wb.y, wb.z, wb.w};
#pragma unroll
            for (int i = 0; i < 4; i++)
#pragma unroll
                for (int f = 0; f < 8; f++)
                    acc[i][f] += xs[i] * ws[f];
        }
    }
#pragma unroll
    for (int i = 0; i < 4; i++) {
        int nd = base + nf * 4 + i;
        float* yp = y + (size_t)nd * DIM + u * 8;
        *(float4*)(yp + 0) = make_float4(acc[i][0], acc[i][1], acc[i][2], acc[i][3]);
        *(float4*)(yp + 4) = make_float4(acc[i][4], acc[i][5], acc[i][6], acc[i][7]);
    }
}

// ---------------- fused aggregate + self + relu + score (epack software prefetch) ----------------
__global__ void fused_agg_kernel(const float* __restrict__ xL, const int2* __restrict__ epack,
                                 const int* __restrict__ eoff, const int* __restrict__ cnt,
                                 const float* __restrict__ dinv,
                                 const float* __restrict__ pw, const float* __restrict__ invn,
                                 float* __restrict__ xA, float* __restrict__ score, int n) {
    int t = threadIdx.x;
    int g = blockIdx.x % NB;
    int chunk = blockIdx.x / NB;
    int ln = chunk * 8 + (t >> 5);
    if (ln >= n) return;
    int node = g * n + ln;
    int lane = t & 31;
    float dsn = dinv[node];
    float4 sv = ((const float4*)(xL + (size_t)node * DIM))[lane];
    float w0 = dsn * dsn;
    float4 a0 = make_float4(sv.x * w0, sv.y * w0, sv.z * w0, sv.w * w0);
    float4 a1 = make_float4(0.f, 0.f, 0.f, 0.f);
    float4 a2 = make_float4(0.f, 0.f, 0.f, 0.f);
    float4 a3 = make_float4(0.f, 0.f, 0.f, 0.f);
    int s0 = eoff[node], s1 = s0 + cnt[node];
    int j = s0;
    int2 e0, e1, e2, e3;
    if (j + 3 < s1) { e0 = epack[j]; e1 = epack[j + 1]; e2 = epack[j + 2]; e3 = epack[j + 3]; }
    for (; j + 7 < s1; j += 4) {
        // prefetch next quad while current rows load
        int2 f0 = epack[j + 4], f1 = epack[j + 5], f2 = epack[j + 6], f3 = epack[j + 7];
        float4 x0 = ((const float4*)(xL + (size_t)e0.x * DIM))[lane];
        float4 x1 = ((const float4*)(xL + (size_t)e1.x * DIM))[lane];
        float4 x2 = ((const float4*)(xL + (size_t)e2.x * DIM))[lane];
        float4 x3 = ((const float4*)(xL + (size_t)e3.x * DIM))[lane];
        float n0 = __int_as_float(e0.y), n1 = __int_as_float(e1.y);
        float n2 = __int_as_float(e2.y), n3 = __int_as_float(e3.y);
        a0.x += n0 * x0.x; a0.y += n0 * x0.y; a0.z += n0 * x0.z; a0.w += n0 * x0.w;
        a1.x += n1 * x1.x; a1.y += n1 * x1.y; a1.z += n1 * x1.z; a1.w += n1 * x1.w;
        a2.x += n2 * x2.x; a2.y += n2 * x2.y; a2.z += n2 * x2.z; a2.w += n2 * x2.w;
        a3.x += n3 * x3.x; a3.y += n3 * x3.y; a3.z += n3 * x3.z; a3.w += n3 * x3.w;
        e0 = f0; e1 = f1; e2 = f2; e3 = f3;
    }
    if (j + 3 < s1) {
        float4 x0 = ((const float4*)(xL + (size_t)e0.x * DIM))[lane];
        float4 x1 = ((const float4*)(xL + (size_t)e1.x * DIM))[lane];
        float4 x2 = ((const float4*)(xL + (size_t)e2.x * DIM))[lane];
        float4 x3 = ((const float4*)(xL + (size_t)e3.x * DIM))[lane];
        float n0 = __int_as_float(e0.y), n1 = __int_as_float(e1.y);
        float n2 = __int_as_float(e2.y), n3 = __int_as_float(e3.y);
        a0.x += n0 * x0.x; a0.y += n0 * x0.y; a0.z += n0 * x0.z; a0.w += n0 * x0.w;
        a1.x += n1 * x1.x; a1.y += n1 * x1.y; a1.z += n1 * x1.z; a1.w += n1 * x1.w;
        a2.x += n2 * x2.x; a2.y += n2 * x2.y; a2.z += n2 * x2.z; a2.w += n2 * x2.w;
        a3.x += n3 * x3.x; a3.y += n3 * x3.y; a3.z += n3 * x3.z; a3.w += n3 * x3.w;
        j += 4;
    }
    for (; j < s1; j++) {
        int2 eq = epack[j];
        float nq = __int_as_float(eq.y);
        float4 xq = ((const float4*)(xL + (size_t)eq.x * DIM))[lane];
        a0.x += nq * xq.x; a0.y += nq * xq.y; a0.z += nq * xq.z; a0.w += nq * xq.w;
    }
    float4 acc = make_float4(fmaxf(a0.x + a1.x + a2.x + a3.x, 0.f),
                             fmaxf(a0.y + a1.y + a2.y + a3.y, 0.f),
                             fmaxf(a0.z + a1.z + a2.z + a3.z, 0.f),
                             fmaxf(a0.w + a1.w + a2.w + a3.w, 0.f));
    ((float4*)(xA + (size_t)node * DIM))[lane] = acc;
    float4 pv = ((const float4*)pw)[lane];
    float dot = acc.x * pv.x + acc.y * pv.y + acc.z * pv.z + acc.w * pv.w;
    for (int off = 16; off >= 1; off >>= 1) dot += __shfl_xor(dot, off, 32);
    if (lane == 0) score[node] = tanhf(dot * invn[0]);
}

// ---------------- pool: sort + gather/readout (+ CSR rebuild | inline head on last) ----------------
__global__ __launch_bounds__(1024) void pool_kernel(const float* __restrict__ score,
                              const float* __restrict__ xA, float* __restrict__ xn,
                              float* __restrict__ h, int* __restrict__ src,
                              int* __restrict__ dst, int2* __restrict__ epack,
                              int* __restrict__ eoff, int* __restrict__ cnt,
                              float* __restrict__ dinv, const float* __restrict__ pwN,
                              float* __restrict__ invn, int n, int k, int last,
                              const float* __restrict__ l1w, const float* __restrict__ l1b,
                              const float* __restrict__ l2w, const float* __restrict__ l2b,
                              const float* __restrict__ l3w, const float* __restrict__ l3b,
                              float* __restrict__ out) {
    __shared__ float keyS[2][1024];
    __shared__ int idxS[2][1024];
    __shared__ int nid[1024];
    __shared__ float4 smax[32][33];
    __shared__ float4 ssum[32][33];
    __shared__ int hs[1024], hc[1024], cur[1024];
    __shared__ float dv[1024];
    __shared__ float shf[128];
    __shared__ int wsum[16];
    __shared__ float hr[256], h1[128], h2[64], lz[2];
    int g = blockIdx.x, t = threadIdx.x;
    int lane = t & 63, wv = t >> 6;
    int b0 = g * EPG, gn = g * n, gk = g * k;
    float k_r = (t < n) ? score[g * n + t] : -2.0f;
    int i_r = t;
    hs[t] = 0; hc[t] = 0;
    // preload edge registers early (independent of sort) to hide latency under sort
    int se[EPT], de[EPT];
    if (!last) {
#pragma unroll
        for (int q = 0; q < EPT; q++) {
            int e = b0 + q * 1024 + t;
            se[q] = src[e];
            de[q] = dst[e];
        }
    }
    int par = 0;
    for (unsigned ksz = 2; ksz <= 1024; ksz <<= 1) {
        for (unsigned jj = ksz >> 1; jj > 0; jj >>= 1) {
            float kq; int iq;
            if (jj >= 64) {
                keyS[par][t] = k_r; idxS[par][t] = i_r;
                __syncthreads();
                kq = keyS[par][t ^ jj]; iq = idxS[par][t ^ jj];
                par ^= 1;
            } else {
                kq = __shfl_xor(k_r, (int)jj, 64);
                iq = __shfl_xor(i_r, (int)jj, 64);
            }
            bool mineFirst = (k_r > kq) || (k_r == kq && i_r < iq);
            bool up = ((t & ksz) == 0);
            bool iAmLower = ((t & jj) == 0);
            bool keepMine = (iAmLower == up) ? mineFirst : !mineFirst;
            if (!keepMine) { k_r = kq; i_r = iq; }
        }
    }
    keyS[0][t] = k_r; idxS[0][t] = i_r;
    nid[i_r] = (t < (unsigned)k) ? t : -1;
    __syncthreads();
    // ---- gather xn = xA[perm]*s + readout max/mean ----
    int lane4 = t & 31;
    int ch = t >> 5;
    float4 mx = make_float4(-INFINITY, -INFINITY, -INFINITY, -INFINITY);
    float4 sm = make_float4(0.f, 0.f, 0.f, 0.f);
    for (int j = ch; j < k; j += 32) {
        int row = idxS[0][j];
        float sval = keyS[0][j];
        float4 vv = ((const float4*)(xA + ((size_t)g * n + row) * DIM))[lane4];
        vv.x *= sval; vv.y *= sval; vv.z *= sval; vv.w *= sval;
        if (!last) ((float4*)(xn + ((size_t)g * k + j) * DIM))[lane4] = vv;
        mx.x = fmaxf(mx.x, vv.x); mx.y = fmaxf(mx.y, vv.y);
        mx.z = fmaxf(mx.z, vv.z); mx.w = fmaxf(mx.w, vv.w);
        sm.x += vv.x; sm.y += vv.y; sm.z += vv.z; sm.w += vv.w;
    }
    smax[ch][lane4] = mx;
    ssum[ch][lane4] = sm;
    __syncthreads();
    for (int s = 16; s >= 1; s >>= 1) {
        if (ch < s) {
            float4 a = smax[ch][lane4], bb = smax[ch + s][lane4];
            a.x = fmaxf(a.x, bb.x); a.y = fmaxf(a.y, bb.y);
            a.z = fmaxf(a.z, bb.z); a.w = fmaxf(a.w, bb.w);
            smax[ch][lane4] = a;
            float4 c = ssum[ch][lane4], d = ssum[ch + s][lane4];
            c.x += d.x; c.y += d.y; c.z += d.z; c.w += d.w;
            ssum[ch][lane4] = c;
        }
        __syncthreads();
    }
    if (ch == 0) {
        float4 m = smax[0][lane4];
        float4 s4 = ssum[0][lane4];
        float invk = 1.0f / (float)k;
        int f0 = lane4 * 4;
        if (!last) {
            float* hp = h + g * 256;
            hp[f0 + 0] += m.x; hp[f0 + 1] += m.y; hp[f0 + 2] += m.z; hp[f0 + 3] += m.w;
            hp[128 + f0 + 0] += s4.x * invk; hp[128 + f0 + 1] += s4.y * invk;
            hp[128 + f0 + 2] += s4.z * invk; hp[128 + f0 + 3] += s4.w * invk;
        } else {
            const float* hp = h + g * 256;
            hr[f0 + 0] = hp[f0 + 0] + m.x; hr[f0 + 1] = hp[f0 + 1] + m.y;
            hr[f0 + 2] = hp[f0 + 2] + m.z; hr[f0 + 3] = hp[f0 + 3] + m.w;
            hr[128 + f0 + 0] = hp[128 + f0 + 0] + s4.x * invk;
            hr[128 + f0 + 1] = hp[128 + f0 + 1] + s4.y * invk;
            hr[128 + f0 + 2] = hp[128 + f0 + 2] + s4.z * invk;
            hr[128 + f0 + 3] = hp[128 + f0 + 3] + s4.w * invk;
        }
    }
    if (last) {
        __syncthreads();
        if (t < 128) {
            float a1 = l1b[t];
            for (int d = 0; d < 256; d++) a1 += hr[d] * l1w[t * 256 + d];
            h1[t] = fmaxf(a1, 0.f);
        }
        __syncthreads();
        if (t < 64) {
            float a2 = l2b[t];
            for (int d = 0; d < 128; d++) a2 += h1[d] * l2w[t * 128 + d];
            h2[t] = fmaxf(a2, 0.f);
        }
        __syncthreads();
        if (t < 2) {
            float a3 = l3b[t];
            for (int d = 0; d < 64; d++) a3 += h2[d] * l3w[t * 64 + d];
            lz[t] = a3;
        }
        __syncthreads();
        if (t < 2) {
            float z0 = lz[0], z1 = lz[1];
            float m = fmaxf(z0, z1);
            float lse = m + logf(expf(z0 - m) + expf(z1 - m));
            out[g * 2 + t] = lz[t] - lse;
        }
        return;
    }
    // ---- remap edges (preloaded registers) + next-layer deg/cnt histogram ----
    int sr[EPT], dr[EPT];
#pragma unroll
    for (int q = 0; q < EPT; q++) {
        int e = b0 + q * 1024 + t;
        int s = se[q];
        int s2 = -1, d2 = -1;
        if (s >= 0) {
            s2 = nid[s - gn];
            d2 = nid[de[q] - gn];
            if (s2 >= 0 && d2 >= 0) {
                src[e] = gk + s2;
                dst[e] = gk + d2;
                atomicAdd(&hs[s2], 1);
                atomicAdd(&hc[d2], 1);
            } else {
                src[e] = -1;
                dst[e] = -1;
                s2 = -1;
            }
        }
        sr[q] = s2; dr[q] = d2;
    }
    __syncthreads();
    // ---- two-level exclusive scan of hc; dinv for next layer ----
    int v = (t < k) ? hc[t] : 0;
    if (t < k) dv[t] = rsqrtf((float)hs[t] + 1.0f);
    int s = v;
#pragma unroll
    for (int off = 1; off < 64; off <<= 1) {
        int u = __shfl_up(s, off, 64);
        if (lane >= off) s += u;
    }
    if (lane == 63) wsum[wv] = s;
    __syncthreads();
    if (wv == 0) {
        int ws = (lane < 16) ? wsum[lane] : 0;
#pragma unroll
        for (int off = 1; off < 16; off <<= 1) {
            int u = __shfl_up(ws, off, 64);
            if (lane >= off) ws += u;
        }
        if (lane < 16) wsum[lane] = ws;
    }
    __syncthreads();
    if (t < k) {
        int excl = b0 + s + ((wv > 0) ? wsum[wv - 1] : 0) - v;
        eoff[gk + t] = excl;
        cnt[gk + t] = v;
        dinv[gk + t] = dv[t];
        cur[t] = excl;
    }
    __syncthreads();
#pragma unroll
    for (int q = 0; q < EPT; q++) {
        if (sr[q] >= 0) {
            int pos = atomicAdd(&cur[dr[q]], 1);
            epack[pos] = make_int2(gk + sr[q], __float_as_int(dv[sr[q]] * dv[dr[q]]));
        }
    }
    if (g == 0) {
        if (t < 128) shf[t] = pwN[t] * pwN[t];
        __syncthreads();
        for (int q = 64; q > 0; q >>= 1) {
            if (t < q) shf[t] += shf[t + q];
            __syncthreads();
        }
        if (t == 0) invn[0] = rsqrtf(shf[0]);
    }
}

extern "C" void kernel_launch(void* const* d_in, const int* in_sizes, int n_in,
                              void* d_out, int out_size, void* d_ws, size_t ws_size,
                              hipStream_t stream) {
    const float* x_in = (const float*)d_in[0];
    const int* edge_index = (const int*)d_in[1];
    const float *cw[5], *cb[5], *pw[5];
    for (int i = 0; i < 5; i++) {
        cw[i] = (const float*)d_in[3 + 3 * i];
        cb[i] = (const float*)d_in[4 + 3 * i];
        pw[i] = (const float*)d_in[5 + 3 * i];
    }
    const float* l1w = (const float*)d_in[18];
    const float* l1b = (const float*)d_in[19];
    const float* l2w = (const float*)d_in[20];
    const float* l2b = (const float*)d_in[21];
    const float* l3w = (const float*)d_in[22];
    const float* l3b = (const float*)d_in[23];
    float* out = (float*)d_out;

    char* w = (char*)d_ws;
    float* xA    = (float*)w; w += (size_t)65536 * DIM * 4;
    float* xB    = (float*)w; w += (size_t)65536 * DIM * 4;
    float* xL    = (float*)w; w += (size_t)65536 * DIM * 4;
    int*   src   = (int*)w;   w += (size_t)ETOT * 4;
    int*   dst   = (int*)w;   w += (size_t)ETOT * 4;
    int2*  epack = (int2*)w;  w += (size_t)ETOT * 8;
    int*   cnt   = (int*)w;   w += (size_t)65536 * 4;
    int*   eoff  = (int*)w;   w += (size_t)65536 * 4;
    float* dinv  = (float*)w; w += (size_t)65536 * 4;
    float* score = (float*)w; w += (size_t)65536 * 4;
    float* hsum  = (float*)w; w += (size_t)NB * 256 * 4;
    float* invn  = (float*)w; w += 4;

    init_kernel<<<NB, 1024, 0, stream>>>(edge_index, src, dst, epack, eoff, cnt, dinv,
                                         invn, pw[0], hsum);

    const float* xin = x_in;
    for (int i = 0; i < 5; i++) {
        int n = NS_H[i], k = NS_H[i + 1];
        int N = NB * n;

        linear_kernel<<<N / 64, 256, 0, stream>>>(xin, cw[i], cb[i], xL, N);
        int gpb = (n + 7) / 8;
        fused_agg_kernel<<<NB * gpb, 256, 0, stream>>>(xL, epack, eoff, cnt, dinv, pw[i],
                                                       invn, xA, score, n);
        pool_kernel<<<NB, 1024, 0, stream>>>(score, xA, xB, hsum, src, dst, epack, eoff,
                                             cnt, dinv, (i < 4) ? pw[i + 1] : pw[i], invn,
                                             n, k, (i == 4) ? 1 : 0,
                                             l1w, l1b, l2w, l2b, l3w, l3b, out);

        xin = xB;
    }
}